// Round 1
// baseline (256.257 us; speedup 1.0000x reference)
//
#include <hip/hip_runtime.h>
#include <hip/hip_bf16.h>
#include <stdint.h>

#define E_N   30000
#define C_IN  128
#define C_OUT 256
#define B_N   4
#define KTAP  5
#define BN    64
#define KSTEPS 20   /* 640 / 32 */

typedef short bf16x8 __attribute__((ext_vector_type(8)));
typedef float f32x4  __attribute__((ext_vector_type(4)));

static __device__ __forceinline__ unsigned short f2bf(float f) {
    union { float f; uint32_t u; } v; v.f = f;
    uint32_t r = (v.u + 0x7FFFu + ((v.u >> 16) & 1u)) >> 16;
    return (unsigned short)r;
}
static __device__ __forceinline__ float bf2f(uint32_t h) {
    union { uint32_t u; float f; } v; v.u = h << 16;
    return v.f;
}

// ---------------------------------------------------------------------------
// Pack conv_w [256][128][5] f32 -> bf16 A-fragments, K reordered tap-major:
// kappa = tap*128 + c.  Fragment layout for mfma_f32_16x16x32_bf16 A-operand:
// lane holds A[m = mt*16 + (lane&15)][k = s*32 + (lane>>4)*8 + j], j=0..7.
// Linear halfword index: ((s*16 + mt)*64 + lane)*8 + j.
// ---------------------------------------------------------------------------
__global__ void pack_w_kernel(const float* __restrict__ w,
                              unsigned short* __restrict__ wp) {
    int tid = blockIdx.x * blockDim.x + threadIdx.x;   // 20480 threads total
    if (tid >= KSTEPS * 16 * 64) return;
    int s    = tid >> 10;
    int mt   = (tid >> 6) & 15;
    int lane = tid & 63;
    int m    = mt * 16 + (lane & 15);
    int kb   = s * 32 + ((lane >> 4) & 3) * 8;
    uint32_t pv[4];
    for (int jj = 0; jj < 4; ++jj) {
        unsigned short lo, hi;
        {
            int kk = kb + 2 * jj;
            int t = kk >> 7, c = kk & 127;
            lo = f2bf(w[(m * C_IN + c) * KTAP + t]);
        }
        {
            int kk = kb + 2 * jj + 1;
            int t = kk >> 7, c = kk & 127;
            hi = f2bf(w[(m * C_IN + c) * KTAP + t]);
        }
        pv[jj] = (uint32_t)lo | ((uint32_t)hi << 16);
    }
    uint4 val; val.x = pv[0]; val.y = pv[1]; val.z = pv[2]; val.w = pv[3];
    *(uint4*)(wp + (size_t)tid * 8) = val;
}

// ---------------------------------------------------------------------------
// Transpose x [B][C][E] f32 -> xT [B][E][C] bf16 so neighbor gathers are
// contiguous in channels (coalesced 16B/lane reads in the GEMM).
// ---------------------------------------------------------------------------
__global__ void transpose_kernel(const float* __restrict__ x,
                                 unsigned short* __restrict__ xT) {
    __shared__ float ld[C_IN][64 + 1];
    int b  = blockIdx.y;
    int e0 = blockIdx.x * 64;
    int t  = threadIdx.x;
    bool full = (e0 + 64 <= E_N);
    for (int pass = 0; pass < 8; ++pass) {
        int c  = pass * 16 + (t >> 4);
        int eo = (t & 15) * 4;
        if (full) {
            const float4 v = *(const float4*)(x + ((size_t)(b * C_IN + c) * E_N + e0 + eo));
            ld[c][eo] = v.x; ld[c][eo + 1] = v.y; ld[c][eo + 2] = v.z; ld[c][eo + 3] = v.w;
        } else {
            for (int i = 0; i < 4; ++i) {
                int e = e0 + eo + i;
                ld[c][eo + i] = (e < E_N) ? x[(size_t)(b * C_IN + c) * E_N + e] : 0.f;
            }
        }
    }
    __syncthreads();
    for (int pass = 0; pass < 8; ++pass) {
        int el = pass * 8 + (t >> 5);
        int c0 = (t & 31) * 4;
        int e  = e0 + el;
        if (e < E_N) {
            ushort4 v;
            v.x = f2bf(ld[c0 + 0][el]);
            v.y = f2bf(ld[c0 + 1][el]);
            v.z = f2bf(ld[c0 + 2][el]);
            v.w = f2bf(ld[c0 + 3][el]);
            *(ushort4*)(xT + (size_t)(b * E_N + e) * C_IN + c0) = v;
        }
    }
}

// ---------------------------------------------------------------------------
// Fused gather + GEMM.  Tile: BM=256 (all C_out) x BN=64 columns, K=640 in
// 20 steps of 32 (tap-major: step s -> tap s>>2, channel base (s&3)*32).
// Block = 256 threads = 4 waves; wave w owns output rows [w*64, w*64+64).
// ---------------------------------------------------------------------------
__launch_bounds__(256)
__global__ void mesh_gemm(const unsigned short* __restrict__ wp,
                          const unsigned short* __restrict__ xT,
                          const int* __restrict__ ne,
                          const float* __restrict__ bias,
                          float* __restrict__ out) {
    __shared__ __align__(16) unsigned short gbuf[BN][40];  // 40: bank-conflict pad
    __shared__ int nbr[BN][4];

    int b    = blockIdx.y;
    int e0   = blockIdx.x * BN;
    int tid  = threadIdx.x;
    int lane = tid & 63;
    int wave = tid >> 6;

    // neighbor indices for this block's 64 columns (clamped at tail)
    {
        int col = tid >> 2, j = tid & 3;
        int e = e0 + col; if (e >= E_N) e = E_N - 1;
        nbr[col][j] = ne[((size_t)b * E_N + e) * 4 + j];
    }
    __syncthreads();

    f32x4 acc[4][4];
    for (int mt = 0; mt < 4; ++mt)
        for (int nt = 0; nt < 4; ++nt)
            acc[mt][nt] = (f32x4){0.f, 0.f, 0.f, 0.f};

    const int col    = tid >> 2;
    const int c8     = (tid & 3) * 8;
    int self_e       = e0 + col; if (self_e >= E_N) self_e = E_N - 1;
    const uint4* wp16 = (const uint4*)wp;

    for (int s = 0; s < KSTEPS; ++s) {
        const int tap = s >> 2;
        const int cb  = (s & 3) * 32;

        // A-fragments: direct coalesced global (L2) loads, independent of LDS
        bf16x8 af[4];
        for (int mt = 0; mt < 4; ++mt) {
            int mtg = wave * 4 + mt;
            uint4 v = wp16[(s * 16 + mtg) * 64 + lane];
            af[mt] = *(bf16x8*)&v;
        }

        __syncthreads();  // previous step's gbuf reads are done

        // Build 32(k) x 64(n) G-tile: each thread -> 8 bf16 (one col, 8 ch)
        {
            uint4 gval;
            if (tap == 0) {
                gval = *(const uint4*)(xT + ((size_t)(b * E_N + self_e) * C_IN + cb + c8));
            } else {
                int j1 = (tap == 1 || tap == 3) ? 0 : 1;
                int s1 = nbr[col][j1];
                int s2 = nbr[col][j1 + 2];
                uint4 v1 = *(const uint4*)(xT + ((size_t)(b * E_N + s1) * C_IN + cb + c8));
                uint4 v2 = *(const uint4*)(xT + ((size_t)(b * E_N + s2) * C_IN + cb + c8));
                const bool isabs = (tap >= 3);
                uint32_t* a1 = (uint32_t*)&v1;
                uint32_t* a2 = (uint32_t*)&v2;
                uint32_t* g  = (uint32_t*)&gval;
                for (int i = 0; i < 4; ++i) {
                    float x0 = bf2f(a1[i] & 0xFFFFu), x1 = bf2f(a1[i] >> 16);
                    float y0 = bf2f(a2[i] & 0xFFFFu), y1 = bf2f(a2[i] >> 16);
                    float r0 = isabs ? fabsf(x0 - y0) : (x0 + y0);
                    float r1 = isabs ? fabsf(x1 - y1) : (x1 + y1);
                    g[i] = (uint32_t)f2bf(r0) | ((uint32_t)f2bf(r1) << 16);
                }
            }
            *(uint4*)(&gbuf[col][c8]) = gval;
        }
        __syncthreads();

        // B-fragments from LDS + MFMA
        bf16x8 bfr[4];
        const int nl_lo = lane & 15;
        const int k8    = ((lane >> 4) & 3) * 8;
        for (int nt = 0; nt < 4; ++nt)
            bfr[nt] = *(const bf16x8*)(&gbuf[nt * 16 + nl_lo][k8]);

        for (int nt = 0; nt < 4; ++nt)
            for (int mt = 0; mt < 4; ++mt)
                acc[mt][nt] = __builtin_amdgcn_mfma_f32_16x16x32_bf16(
                    af[mt], bfr[nt], acc[mt][nt], 0, 0, 0);
    }

    // Epilogue: C/D layout col = lane&15, row = (lane>>4)*4 + r
    const int quad = lane >> 4;
    const int ecol = lane & 15;
    for (int mt = 0; mt < 4; ++mt) {
        int o_base = (wave * 4 + mt) * 16 + quad * 4;
        for (int r = 0; r < 4; ++r) {
            int o = o_base + r;
            float bv = bias[o];
            for (int nt = 0; nt < 4; ++nt) {
                int e = e0 + nt * 16 + ecol;
                if (e < E_N)
                    out[((size_t)(b * C_OUT + o)) * E_N + e] = acc[mt][nt][r] + bv;
            }
        }
    }
}

// ---------------------------------------------------------------------------
// Fallback (ws too small): direct fp32 compute, slow but correct.
// ---------------------------------------------------------------------------
__global__ void fallback_kernel(const float* __restrict__ x,
                                const int* __restrict__ ne,
                                const float* __restrict__ w,
                                const float* __restrict__ bias,
                                float* __restrict__ out) {
    size_t id = (size_t)blockIdx.x * blockDim.x + threadIdx.x;
    if (id >= (size_t)B_N * C_OUT * E_N) return;
    int e = (int)(id % E_N);
    int o = (int)((id / E_N) % C_OUT);
    int b = (int)(id / ((size_t)E_N * C_OUT));
    const int4 nb = *(const int4*)(ne + ((size_t)b * E_N + e) * 4);
    float acc = bias[o];
    for (int c = 0; c < C_IN; ++c) {
        const float* xb = x + (size_t)(b * C_IN + c) * E_N;
        float s0 = xb[e];
        float x1 = xb[nb.x], x2 = xb[nb.y], x3 = xb[nb.z], x4 = xb[nb.w];
        const float* wo = w + (size_t)(o * C_IN + c) * KTAP;
        acc += wo[0] * s0
             + wo[1] * (x1 + x3)
             + wo[2] * (x2 + x4)
             + wo[3] * fabsf(x1 - x3)
             + wo[4] * fabsf(x2 - x4);
    }
    out[id] = acc;
}

extern "C" void kernel_launch(void* const* d_in, const int* in_sizes, int n_in,
                              void* d_out, int out_size, void* d_ws, size_t ws_size,
                              hipStream_t stream) {
    const float* x      = (const float*)d_in[0];
    const int*   ne_idx = (const int*)d_in[1];
    const float* conv_w = (const float*)d_in[2];
    const float* conv_b = (const float*)d_in[3];
    float* out = (float*)d_out;

    const size_t wp_bytes = (size_t)C_OUT * 640 * 2;          // 327,680
    const size_t xT_off   = 512 * 1024;
    const size_t need     = xT_off + (size_t)B_N * E_N * C_IN * 2;  // ~31.2 MB

    if (ws_size < need) {
        size_t total = (size_t)B_N * C_OUT * E_N;
        int blocks = (int)((total + 255) / 256);
        fallback_kernel<<<blocks, 256, 0, stream>>>(x, ne_idx, conv_w, conv_b, out);
        return;
    }
    (void)wp_bytes;

    unsigned short* wp = (unsigned short*)d_ws;
    unsigned short* xT = (unsigned short*)((char*)d_ws + xT_off);

    pack_w_kernel<<<80, 256, 0, stream>>>(conv_w, wp);
    dim3 tg((E_N + 63) / 64, B_N);
    transpose_kernel<<<tg, 256, 0, stream>>>(x, xT);
    dim3 gg((E_N + BN - 1) / BN, B_N);
    mesh_gemm<<<gg, 256, 0, stream>>>(wp, xT, ne_idx, conv_b, out);
}